// Round 1
// baseline (1040.000 us; speedup 1.0000x reference)
//
#include <hip/hip_runtime.h>
#include <math.h>

#define B_  32
#define C_  384
#define CH_ 96
#define HH  32
#define WW  32
#define HW  (HH*WW)

struct KParams {
  const float* x;
  const float* mw1[3]; const float* mb1[3]; const float* mw2[3]; const float* mb2[3];
  const float* cw[3];  const float* cb[3];
  const float* fw1; const float* fb1; const float* fw2; const float* fb2;
  const float* pw;  const float* pb;
  float* a;    // [B][C] sums of (x1+x2+x3) over H,W
  float* wg;   // [3][B][C] softmax gates
  float* out;  // [B][C][H][W]
};

__device__ __forceinline__ float gelu_exact(float v) {
  return 0.5f * v * (1.0f + erff(v * 0.70710678118654752440f));
}

// ---------------------------------------------------------------------------
// Kernel 1: compute per-channel spatial sums of (x1+x2+x3) into a[B][C].
// grid = B * 4 chunks * 4 row-tiles = 512 blocks, 256 threads (1 thread/pixel)
// ---------------------------------------------------------------------------
__global__ __launch_bounds__(256) void k_branch_sum(KParams P) {
  const int bid = blockIdx.x;
  const int b  = bid >> 4;
  const int ci = (bid >> 2) & 3;
  const int ht = bid & 3;
  const int t  = threadIdx.x;
  const int hh = ht * 8 + (t >> 5);
  const int p  = t & 31;

  __shared__ float accl[CH_];
  __shared__ float w1l[3*1152], w2l[3*1152], b1l[36], b2l[288];
  if (t < CH_) accl[t] = 0.f;

  if ((ci & 1) == 0) {
    // ---- MLP chunk (all 3 branches) ----
    const int mi = ci >> 1;
    for (int idx = t; idx < 3*1152; idx += 256) {
      int s = idx / 1152, r = idx - s*1152;
      w1l[idx] = P.mw1[s][mi*1152 + r];
      w2l[idx] = P.mw2[s][mi*1152 + r];
    }
    if (t < 36)  b1l[t] = P.mb1[t/12][mi*12 + (t%12)];
    for (int idx = t; idx < 288; idx += 256) b2l[idx] = P.mb2[idx/96][mi*96 + (idx%96)];
    __syncthreads();

    float h[3][12];
#pragma unroll
    for (int s = 0; s < 3; ++s)
#pragma unroll
      for (int j = 0; j < 12; ++j) h[s][j] = b1l[s*12+j];

    const float* xp = P.x + ((size_t)(b*C_ + ci*CH_) * HH + hh) * WW + p;
    for (int c = 0; c < CH_; ++c) {
      float xc = xp[(size_t)c * HW];
#pragma unroll
      for (int s = 0; s < 3; ++s)
#pragma unroll
        for (int j = 0; j < 12; ++j) h[s][j] += xc * w1l[s*1152 + c*12 + j];
    }
#pragma unroll
    for (int s = 0; s < 3; ++s)
#pragma unroll
      for (int j = 0; j < 12; ++j) h[s][j] = gelu_exact(h[s][j]);

    for (int c = 0; c < CH_; ++c) {
      float ys = 0.f;
#pragma unroll
      for (int s = 0; s < 3; ++s) {
        float y = b2l[s*96 + c];
#pragma unroll
        for (int j = 0; j < 12; ++j) y += h[s][j] * w2l[s*1152 + j*96 + c];
        ys += y;
      }
#pragma unroll
      for (int m = 32; m >= 1; m >>= 1) ys += __shfl_xor(ys, m, 64);
      if ((t & 63) == 0) atomicAdd(&accl[c], ys);
    }
  } else {
    // ---- depthwise-conv chunk (k=1,3,5 for branches 0,1,2) ----
    const int gi = ci >> 1;
    __syncthreads();
    const float* xb = P.x + (size_t)(b*C_ + ci*CH_) * HW;
    for (int c = 0; c < CH_; ++c) {
      const float* xc = xb + (size_t)c * HW;
      float ys = xc[hh*32 + p] * P.cw[0][gi*96 + c]
               + P.cb[0][gi*96 + c] + P.cb[1][gi*96 + c] + P.cb[2][gi*96 + c];
      const float* w3 = P.cw[1] + (gi*96 + c) * 9;
#pragma unroll
      for (int dy = 0; dy < 3; ++dy) {
        int hy = hh + dy - 1;
        if (hy < 0 || hy >= 32) continue;
#pragma unroll
        for (int dx = 0; dx < 3; ++dx) {
          int wx = p + dx - 1;
          if (wx < 0 || wx >= 32) continue;
          ys += xc[hy*32 + wx] * w3[dy*3 + dx];
        }
      }
      const float* w5 = P.cw[2] + (gi*96 + c) * 25;
#pragma unroll
      for (int dy = 0; dy < 5; ++dy) {
        int hy = hh + dy - 2;
        if (hy < 0 || hy >= 32) continue;
#pragma unroll
        for (int dx = 0; dx < 5; ++dx) {
          int wx = p + dx - 2;
          if (wx < 0 || wx >= 32) continue;
          ys += xc[hy*32 + wx] * w5[dy*5 + dx];
        }
      }
#pragma unroll
      for (int m = 32; m >= 1; m >>= 1) ys += __shfl_xor(ys, m, 64);
      if ((t & 63) == 0) atomicAdd(&accl[c], ys);
    }
  }
  __syncthreads();
  if (t < CH_) atomicAdd(&P.a[b*C_ + ci*CH_ + t], accl[t]);
}

// ---------------------------------------------------------------------------
// Kernel 2: gating MLP + softmax over the 3 scales.  grid = B, 128 threads.
// ---------------------------------------------------------------------------
__global__ __launch_bounds__(128) void k_gate(KParams P) {
  const int b = blockIdx.x, t = threadIdx.x;
  __shared__ float am[C_], g1[96];
  for (int idx = t; idx < C_; idx += 128) am[idx] = P.a[b*C_ + idx] * (1.0f/1024.0f);
  __syncthreads();
  if (t < 96) {
    float acc = P.fb1[t];
    for (int c = 0; c < C_; ++c) acc += am[c] * P.fw1[c*96 + t];
    g1[t] = gelu_exact(acc);
  }
  __syncthreads();
  for (int c = t; c < C_; c += 128) {
    float l0 = P.fb2[c*3+0], l1 = P.fb2[c*3+1], l2 = P.fb2[c*3+2];
    for (int j = 0; j < 96; ++j) {
      float g = g1[j];
      const float* f = P.fw2 + j*1152 + c*3;
      l0 += g * f[0]; l1 += g * f[1]; l2 += g * f[2];
    }
    float m = fmaxf(l0, fmaxf(l1, l2));
    float e0 = expf(l0 - m), e1 = expf(l1 - m), e2 = expf(l2 - m);
    float inv = 1.0f / (e0 + e1 + e2);
    P.wg[0*(B_*C_) + b*C_ + c] = e0 * inv;
    P.wg[1*(B_*C_) + b*C_ + c] = e1 * inv;
    P.wg[2*(B_*C_) + b*C_ + c] = e2 * inv;
  }
}

// ---------------------------------------------------------------------------
// Kernel 3: recompute branches, gate-combine into LDS, project 384->384.
// grid = B * H = 1024 blocks (one image-row each), 256 threads.
// ---------------------------------------------------------------------------
__global__ __launch_bounds__(256) void k_main(KParams P) {
  const int bid = blockIdx.x;
  const int b  = bid >> 5;
  const int hh = bid & 31;
  const int t  = threadIdx.x;

  __shared__ float comb[C_ * 32];   // [c][p]  48 KiB
  __shared__ float hl[3 * 12 * 32]; // [s][j][p]

  for (int ci = 0; ci < 4; ++ci) {
    if ((ci & 1) == 0) {
      const int mi = ci >> 1;
      // first layer: tasks (s, j, p)
      for (int idx = t; idx < 1152; idx += 256) {
        int s = idx / 384, r = idx - s*384, j = r >> 5, p = r & 31;
        float acc = P.mb1[s][mi*12 + j];
        const float* xp = P.x + ((size_t)(b*C_ + ci*CH_) * HH + hh) * WW + p;
        const float* w1 = P.mw1[s] + mi*1152 + j;
        for (int c = 0; c < CH_; ++c) acc += xp[(size_t)c*HW] * w1[c*12];
        hl[idx] = gelu_exact(acc);     // idx == (s*12+j)*32 + p
      }
      __syncthreads();
      // second layer + gate
      for (int idx = t; idx < 3072; idx += 256) {
        int c = idx >> 5, p = idx & 31, gc = ci*CH_ + c;
        float val = 0.f;
#pragma unroll
        for (int s = 0; s < 3; ++s) {
          float y = P.mb2[s][mi*96 + c];
          const float* w2 = P.mw2[s] + mi*1152 + c;
#pragma unroll
          for (int j = 0; j < 12; ++j) y += hl[(s*12+j)*32 + p] * w2[j*96];
          val += P.wg[s*(B_*C_) + b*C_ + gc] * y;
        }
        comb[gc*32 + p] = val;
      }
      __syncthreads();
    } else {
      const int gi = ci >> 1;
      for (int idx = t; idx < 3072; idx += 256) {
        int c = idx >> 5, p = idx & 31, gc = ci*CH_ + c;
        const float* xc = P.x + (size_t)(b*C_ + gc) * HW;
        float y0 = xc[hh*32 + p] * P.cw[0][gi*96 + c] + P.cb[0][gi*96 + c];
        float y1 = P.cb[1][gi*96 + c];
        const float* w3 = P.cw[1] + (gi*96 + c) * 9;
#pragma unroll
        for (int dy = 0; dy < 3; ++dy) {
          int hy = hh + dy - 1;
          if (hy < 0 || hy >= 32) continue;
#pragma unroll
          for (int dx = 0; dx < 3; ++dx) {
            int wx = p + dx - 1;
            if (wx < 0 || wx >= 32) continue;
            y1 += xc[hy*32 + wx] * w3[dy*3 + dx];
          }
        }
        float y2 = P.cb[2][gi*96 + c];
        const float* w5 = P.cw[2] + (gi*96 + c) * 25;
#pragma unroll
        for (int dy = 0; dy < 5; ++dy) {
          int hy = hh + dy - 2;
          if (hy < 0 || hy >= 32) continue;
#pragma unroll
          for (int dx = 0; dx < 5; ++dx) {
            int wx = p + dx - 2;
            if (wx < 0 || wx >= 32) continue;
            y2 += xc[hy*32 + wx] * w5[dy*5 + dx];
          }
        }
        const float* wgp = P.wg + b*C_ + gc;
        comb[gc*32 + p] = wgp[0]*y0 + wgp[B_*C_]*y1 + wgp[2*B_*C_]*y2;
      }
      __syncthreads();
    }
  }

  // ---- projection: out[d][p] = pb[d] + sum_c comb[c][p] * pw[c][d] ----
  const int pd = t & 7,  p0 = pd * 4;
  const int dg = t >> 3, d0 = dg * 12;
  float acc[48];
#pragma unroll
  for (int pp = 0; pp < 4; ++pp)
#pragma unroll
    for (int dd = 0; dd < 12; ++dd) acc[pp*12 + dd] = P.pb[d0 + dd];

  for (int c = 0; c < C_; ++c) {
    const float4 cv = *reinterpret_cast<const float4*>(&comb[c*32 + p0]);
    const float* pr = P.pw + (size_t)c * C_ + d0;
    const float4 w0 = *reinterpret_cast<const float4*>(pr);
    const float4 w1 = *reinterpret_cast<const float4*>(pr + 4);
    const float4 w2 = *reinterpret_cast<const float4*>(pr + 8);
    const float wv[12] = {w0.x,w0.y,w0.z,w0.w, w1.x,w1.y,w1.z,w1.w, w2.x,w2.y,w2.z,w2.w};
    const float cc[4]  = {cv.x,cv.y,cv.z,cv.w};
#pragma unroll
    for (int pp = 0; pp < 4; ++pp)
#pragma unroll
      for (int dd = 0; dd < 12; ++dd) acc[pp*12 + dd] += cc[pp] * wv[dd];
  }
#pragma unroll
  for (int dd = 0; dd < 12; ++dd) {
    float4 o = make_float4(acc[0*12+dd], acc[1*12+dd], acc[2*12+dd], acc[3*12+dd]);
    *reinterpret_cast<float4*>(&P.out[((size_t)(b*C_ + d0 + dd) * HH + hh) * WW + p0]) = o;
  }
}

// ---------------------------------------------------------------------------
extern "C" void kernel_launch(void* const* d_in, const int* in_sizes, int n_in,
                              void* d_out, int out_size, void* d_ws, size_t ws_size,
                              hipStream_t stream) {
  KParams P;
  P.x = (const float*)d_in[0];
  for (int s = 0; s < 3; ++s) {
    const int base = 1 + s * 6;
    P.mw1[s] = (const float*)d_in[base + 0];
    P.mb1[s] = (const float*)d_in[base + 1];
    P.mw2[s] = (const float*)d_in[base + 2];
    P.mb2[s] = (const float*)d_in[base + 3];
    P.cw[s]  = (const float*)d_in[base + 4];
    P.cb[s]  = (const float*)d_in[base + 5];
  }
  P.fw1 = (const float*)d_in[19]; P.fb1 = (const float*)d_in[20];
  P.fw2 = (const float*)d_in[21]; P.fb2 = (const float*)d_in[22];
  P.pw  = (const float*)d_in[23]; P.pb  = (const float*)d_in[24];
  P.a   = (float*)d_ws;
  P.wg  = (float*)d_ws + B_*C_;
  P.out = (float*)d_out;

  hipMemsetAsync(d_ws, 0, B_*C_*sizeof(float), stream);
  k_branch_sum<<<512, 256, 0, stream>>>(P);
  k_gate<<<32, 128, 0, stream>>>(P);
  k_main<<<1024, 256, 0, stream>>>(P);
}

// Round 2
// 280.051 us; speedup vs baseline: 3.7136x; 3.7136x over previous
//
#include <hip/hip_runtime.h>
#include <math.h>

#define B_  32
#define C_  384
#define HW  1024

typedef float          f32x4 __attribute__((ext_vector_type(4)));
typedef short          s16x8 __attribute__((ext_vector_type(8)));
typedef unsigned short us8v  __attribute__((ext_vector_type(8)));

struct KParams {
  const float* x;
  const float* mw1[3]; const float* mb1[3]; const float* mw2[3]; const float* mb2[3];
  const float* cw[3];  const float* cb[3];
  const float* fw1; const float* fb1; const float* fw2; const float* fb2;
  const float* pw;  const float* pb;
  float* wg;            // [3][B][C]
  float* H_part;        // [B][2][8][36]
  float* acv_part;      // [B][2][8][96]
  unsigned short* pwT;  // [384 d][384 k'] bf16, k' permuted
  float* out;
};

__device__ __forceinline__ float gelu_exact(float v) {
  return 0.5f * v * (1.0f + erff(v * 0.70710678118654752440f));
}
__device__ __forceinline__ unsigned short f2bf(float f) {
  unsigned u = __float_as_uint(f);
  u += 0x7FFFu + ((u >> 16) & 1u);
  return (unsigned short)(u >> 16);
}
__device__ __forceinline__ float bf2f(unsigned short h) {
  return __uint_as_float(((unsigned)h) << 16);
}

// ---------------------------------------------------------------------------
// k_prep: pwT[d][k'] = bf16(pw[gc(k')][d]); k' permutation: [mlp0, mlp1, cv0, cv1]
// ---------------------------------------------------------------------------
__global__ __launch_bounds__(256) void k_prep(KParams P) {
  __shared__ float tile[32][33];
  const int td = blockIdx.x % 12, tc = blockIdx.x / 12;
  const int j = threadIdx.x & 31, i0 = threadIdx.x >> 5;
  const int gcoff = (tc < 3) ? 0 : (tc < 6 ? 96 : (tc < 9 ? -96 : 0));
  for (int i = i0; i < 32; i += 8)
    tile[i][j] = P.pw[(size_t)(tc*32 + i + gcoff)*C_ + td*32 + j];
  __syncthreads();
  for (int i = i0; i < 32; i += 8)
    P.pwT[(size_t)(td*32 + i)*C_ + tc*32 + j] = f2bf(tile[j][i]);
}

// ---------------------------------------------------------------------------
// conv window sum for one (channel, 4-row-tile row, 16-pix half): returns
// per-branch y into y0/y1/y2 (k=1/3/5, zero-padded), NO biases.
// ---------------------------------------------------------------------------
template<int HALF>
__device__ __forceinline__ void conv_strip(const float* xc, int h0, int row,
                                           float w1t, const float* w3, const float* w5,
                                           float* y0, float* y1, float* y2) {
#pragma unroll
  for (int p = 0; p < 16; ++p) { y0[p] = 0.f; y1[p] = 0.f; y2[p] = 0.f; }
#pragma unroll
  for (int dy = 0; dy < 5; ++dy) {
    const int hr = h0 + row - 2 + dy;
    float win[20];
    if (hr >= 0 && hr < 32) {
#pragma unroll
      for (int u = 0; u < 5; ++u)
        *(float4*)&win[u*4] = *(const float4*)&xc[hr*32 + HALF*12 + u*4];
    } else {
#pragma unroll
      for (int u = 0; u < 20; ++u) win[u] = 0.f;
    }
#pragma unroll
    for (int dx = 0; dx < 5; ++dx) {
      const float w = w5[dy*5 + dx];
#pragma unroll
      for (int p = 0; p < 16; ++p) {
        const int ri = p + dx - 2 + HALF*4;
        if (ri >= 0 && ri < 20) y2[p] += win[ri] * w;
      }
    }
    if (dy >= 1 && dy <= 3) {
#pragma unroll
      for (int dx = 0; dx < 3; ++dx) {
        const float w = w3[(dy-1)*3 + dx];
#pragma unroll
        for (int p = 0; p < 16; ++p) {
          const int ri = p + dx - 1 + HALF*4;
          if (ri >= 0 && ri < 20) y1[p] += win[ri] * w;
        }
      }
      if (dy == 2) {
#pragma unroll
        for (int p = 0; p < 16; ++p) y0[p] = win[p + HALF*4] * w1t;
      }
    }
  }
}

// ---------------------------------------------------------------------------
// k_sum: grid = b(32) x chunk(4) x rowquad(8), 256 threads.
// MLP chunks -> H_part (sum of gelu(h) over pixels); conv -> acv_part.
// ---------------------------------------------------------------------------
__global__ __launch_bounds__(256, 2) void k_sum(KParams P) {
  __shared__ __align__(16) char sm[49152 + 13824 + 256];
  const int bid = blockIdx.x;
  const int b = bid >> 5, ci = (bid >> 3) & 3, q = bid & 7;
  const int h0 = q * 4;
  const int t = threadIdx.x;

  if ((ci & 1) == 0) {
    const int mi = ci >> 1;
    float* Xl  = (float*)sm;                     // [96][128]
    float* w1l = (float*)(sm + 49152);           // [(s*2+mi-slot flattened) wrong: [s][c][j] for this mi]
    float* Hl  = (float*)(sm + 49152 + 13824);   // [36]
    for (int i = t; i < 3456; i += 256) {
      int s = i / 1152, r = i - s*1152;
      w1l[i] = P.mw1[s][mi*1152 + r];            // layout [s][c][j]
    }
    for (int i = t*4; i < 12288; i += 1024) {
      int c = i >> 7, pix = i & 127;
      *(float4*)&Xl[i] = *(const float4*)&P.x[(size_t)(b*C_ + mi*192 + c)*HW + h0*32 + pix];
    }
    __syncthreads();
    const int quad = t & 31, sjg = t >> 6;       // cq = (t>>5)&1
    const int cq = (t >> 5) & 1;
    const int sj0 = sjg * 9;
    float h[9][4];
#pragma unroll
    for (int u = 0; u < 9; ++u) { h[u][0]=0.f; h[u][1]=0.f; h[u][2]=0.f; h[u][3]=0.f; }
    int wbase[9];
#pragma unroll
    for (int u = 0; u < 9; ++u) {
      int sj = sj0 + u, s = sj / 12, jj = sj % 12;
      wbase[u] = s*1152 + jj;
    }
    for (int c = cq*48; c < cq*48 + 48; ++c) {
      const float4 xv = *(const float4*)&Xl[c*128 + quad*4];
#pragma unroll
      for (int u = 0; u < 9; ++u) {
        const float w = w1l[wbase[u] + c*12];
        h[u][0] += xv.x*w; h[u][1] += xv.y*w; h[u][2] += xv.z*w; h[u][3] += xv.w*w;
      }
    }
#pragma unroll
    for (int u = 0; u < 9; ++u)
#pragma unroll
      for (int p = 0; p < 4; ++p) h[u][p] += __shfl_xor(h[u][p], 32, 64);
    float hs[9];
#pragma unroll
    for (int u = 0; u < 9; ++u) {
      int sj = sj0 + u, s = sj / 12, jj = sj % 12;
      const float bias = P.mb1[s][mi*12 + jj];
      float sum = 0.f;
#pragma unroll
      for (int p = 0; p < 4; ++p) sum += gelu_exact(h[u][p] + bias);
#pragma unroll
      for (int m = 16; m >= 1; m >>= 1) sum += __shfl_xor(sum, m, 64);
      hs[u] = sum;
    }
    if ((t & 63) == 0) {
#pragma unroll
      for (int u = 0; u < 9; ++u) Hl[sj0 + u] = hs[u];
    }
    __syncthreads();
    if (t < 36) P.H_part[(size_t)((b*2 + mi)*8 + q)*36 + t] = Hl[t];
  } else {
    const int gi = ci >> 1;
    float* accl = (float*)sm;
    if (t < 96) accl[t] = 0.f;
    __syncthreads();
    for (int it = 0; it < 2; ++it) {
      const int task = t + 256*it;
      if (task < 384) {
        const int row = task & 3, cc = task >> 2;
        const int gcl = gi*96 + cc;
        const float* xc = P.x + (size_t)(b*C_ + (2*gi+1)*96 + cc)*HW;
        const float w1t = P.cw[0][gcl];
        float w3[9], w5[25];
#pragma unroll
        for (int k2 = 0; k2 < 9; ++k2)  w3[k2] = P.cw[1][gcl*9 + k2];
#pragma unroll
        for (int k2 = 0; k2 < 25; ++k2) w5[k2] = P.cw[2][gcl*25 + k2];
        float val = 0.f;
        {
          float y0[16], y1[16], y2[16];
          conv_strip<0>(xc, h0, row, w1t, w3, w5, y0, y1, y2);
#pragma unroll
          for (int p = 0; p < 16; ++p) val += y0[p] + y1[p] + y2[p];
          conv_strip<1>(xc, h0, row, w1t, w3, w5, y0, y1, y2);
#pragma unroll
          for (int p = 0; p < 16; ++p) val += y0[p] + y1[p] + y2[p];
        }
        atomicAdd(&accl[cc], val);
      }
    }
    __syncthreads();
    if (t < 96) P.acv_part[(size_t)((b*2 + gi)*8 + q)*96 + t] = accl[t];
  }
}

// ---------------------------------------------------------------------------
// k_gate: finish sums -> a[c] -> fusion MLP -> softmax gates. grid=B, 128 thr.
// ---------------------------------------------------------------------------
__global__ __launch_bounds__(128) void k_gate(KParams P) {
  const int b = blockIdx.x, t = threadIdx.x;
  __shared__ float am[C_], g1v[96], Hs[2][36];
  for (int i = t; i < 72; i += 128) {
    int mi = i / 36, sj = i % 36;
    float s = 0.f;
    for (int q = 0; q < 8; ++q) s += P.H_part[(size_t)((b*2+mi)*8 + q)*36 + sj];
    Hs[mi][sj] = s * (1.0f/1024.0f);
  }
  __syncthreads();
  for (int i = t; i < 192; i += 128) {
    int mi = i / 96, cc = i % 96;
    float a = 0.f;
    for (int s = 0; s < 3; ++s) {
      float y = P.mb2[s][mi*96 + cc];
      for (int jj = 0; jj < 12; ++jj) y += Hs[mi][s*12+jj] * P.mw2[s][mi*1152 + jj*96 + cc];
      a += y;
    }
    am[mi*192 + cc] = a;
  }
  for (int i = t; i < 192; i += 128) {
    int gi = i / 96, cc = i % 96;
    float s = 0.f;
    for (int q = 0; q < 8; ++q) s += P.acv_part[(size_t)((b*2+gi)*8 + q)*96 + cc];
    s *= (1.0f/1024.0f);
    for (int sb = 0; sb < 3; ++sb) s += P.cb[sb][gi*96 + cc];
    am[(2*gi+1)*96 + cc] = s;
  }
  __syncthreads();
  if (t < 96) {
    float acc = P.fb1[t];
    for (int c = 0; c < C_; ++c) acc += am[c] * P.fw1[c*96 + t];
    g1v[t] = gelu_exact(acc);
  }
  __syncthreads();
  for (int c = t; c < C_; c += 128) {
    float l0 = P.fb2[c*3+0], l1 = P.fb2[c*3+1], l2 = P.fb2[c*3+2];
    for (int jj = 0; jj < 96; ++jj) {
      const float g = g1v[jj];
      const float* f = P.fw2 + jj*1152 + c*3;
      l0 += g*f[0]; l1 += g*f[1]; l2 += g*f[2];
    }
    const float m = fmaxf(l0, fmaxf(l1, l2));
    const float e0 = expf(l0-m), e1 = expf(l1-m), e2 = expf(l2-m);
    const float inv = 1.0f/(e0+e1+e2);
    P.wg[0*(B_*C_) + b*C_ + c] = e0*inv;
    P.wg[1*(B_*C_) + b*C_ + c] = e1*inv;
    P.wg[2*(B_*C_) + b*C_ + c] = e2*inv;
  }
}

// ---------------------------------------------------------------------------
// k_proj: grid = b(32) x rowquad(8) = 256 blocks, 512 threads.
// Recompute branches -> swizzled bf16 comb[128][384] in LDS -> MFMA GEMM.
// LDS arena: comb 98304 | hl 18432 | X 24576 | wl 13824 | wgl 4608 = 159744 B
// ---------------------------------------------------------------------------
template<int HALF>
__device__ __forceinline__ void conv_phase(const KParams& P, int b, int h0,
                                           char* combB, const float* wgl, int tt) {
  for (int it = 0; it < 3; ++it) {
    const int tid = tt + 256*it;              // 0..767
    const int row = tid & 3, c192 = tid >> 2; // c192 0..191
    const int gi = c192 / 96, cc = c192 - gi*96;
    const int gcl = gi*96 + cc;
    const int gc = (2*gi + 1)*96 + cc;
    const int kp = 192 + gi*96 + cc;
    const float* xc = P.x + (size_t)(b*C_ + gc)*HW;
    const float w1t = P.cw[0][gcl];
    float w3[9], w5[25];
#pragma unroll
    for (int k2 = 0; k2 < 9; ++k2)  w3[k2] = P.cw[1][gcl*9 + k2];
#pragma unroll
    for (int k2 = 0; k2 < 25; ++k2) w5[k2] = P.cw[2][gcl*25 + k2];
    float y0[16], y1[16], y2[16];
    conv_strip<HALF>(xc, h0, row, w1t, w3, w5, y0, y1, y2);
    const float g0 = wgl[0*C_ + gc], g1 = wgl[1*C_ + gc], g2 = wgl[2*C_ + gc];
    const float cbg = g0*P.cb[0][gcl] + g1*P.cb[1][gcl] + g2*P.cb[2][gcl];
#pragma unroll
    for (int p = 0; p < 16; ++p) {
      const float v = g0*y0[p] + g1*y1[p] + g2*y2[p] + cbg;
      const int pix = row*32 + HALF*16 + p;
      const int off = pix*768 + (((kp*2)) ^ ((pix & 15) << 4));
      *(unsigned short*)(combB + off) = f2bf(v);
    }
  }
}

__global__ __launch_bounds__(512, 1) void k_proj(KParams P) {
  __shared__ __align__(16) char smem[159744];
  char* combB = smem;
  char* hlB   = smem + 98304;
  char* XB    = smem + 116736;
  unsigned short* wlB = (unsigned short*)(smem + 141312);
  float* wgl  = (float*)(smem + 155136);

  const int t = threadIdx.x;
  const int b  = blockIdx.x >> 3;
  const int h0 = (blockIdx.x & 7) * 4;

  // stage gates + w1 (bf16)
  for (int i = t; i < 1152; i += 512)
    wgl[i] = P.wg[(size_t)(i/C_)*(B_*C_) + b*C_ + (i % C_)];
  for (int i = t; i < 6912; i += 512) {
    int s = i / 2304, r = i - s*2304, mi2 = r / 1152, rr = r - mi2*1152;
    wlB[i] = f2bf(P.mw1[s][mi2*1152 + rr]);    // layout [(s*2+mi)*1152 + c*12 + j]
  }
  // stage X for mi=0 (bf16 [96][128])
  for (int i = t*4; i < 12288; i += 2048) {
    int c = i >> 7, pix = i & 127;
    float4 v = *(const float4*)&P.x[(size_t)(b*C_ + 0*192 + c)*HW + h0*32 + pix];
    unsigned lo = (unsigned)f2bf(v.x) | ((unsigned)f2bf(v.y) << 16);
    unsigned hi = (unsigned)f2bf(v.z) | ((unsigned)f2bf(v.w) << 16);
    *(uint2*)(XB + c*256 + pix*2) = make_uint2(lo, hi);
  }
  __syncthreads();

  // ---- phase A: layer1(mi=0) on waves 0-3, conv half 0 on waves 4-7 ----
#pragma unroll 1
  for (int mi = 0; mi < 2; ++mi) {
    if (t < 256) {
      const int oct = t & 15, cq = (t >> 4) & 1, sjg = t >> 5;
      const int nsj = (sjg < 4) ? 5 : 4;
      const int sj0 = (sjg < 4) ? sjg*5 : 20 + (sjg - 4)*4;
      int wbase[5]; float bias[5];
#pragma unroll
      for (int u = 0; u < 5; ++u) {
        int sj = sj0 + ((u < 5 && u < nsj) ? u : 0);
        int s = sj / 12, jj = sj - s*12;
        wbase[u] = (s*2 + mi)*1152 + jj;
        bias[u] = P.mb1[s][mi*12 + jj];
      }
      float h[5][8];
#pragma unroll
      for (int u = 0; u < 5; ++u)
#pragma unroll
        for (int p = 0; p < 8; ++p) h[u][p] = 0.f;
      for (int c = cq*48; c < cq*48 + 48; ++c) {
        const us8v xv = *(const us8v*)(XB + c*256 + oct*16);
        float xf[8];
#pragma unroll
        for (int p = 0; p < 8; ++p) xf[p] = bf2f(xv[p]);
#pragma unroll
        for (int u = 0; u < 5; ++u) {
          if (u < nsj) {
            const float w = bf2f(wlB[wbase[u] + c*12]);
#pragma unroll
            for (int p = 0; p < 8; ++p) h[u][p] += xf[p]*w;
          }
        }
      }
#pragma unroll
      for (int u = 0; u < 5; ++u)
#pragma unroll
        for (int p = 0; p < 8; ++p) h[u][p] += __shfl_xor(h[u][p], 16, 64);
      if (cq == 0) {
#pragma unroll
        for (int u = 0; u < 5; ++u) {
          if (u < nsj) {
            us8v o;
#pragma unroll
            for (int p = 0; p < 8; ++p) o[p] = f2bf(gelu_exact(h[u][p] + bias[u]));
            *(us8v*)(hlB + (mi*36 + sj0 + u)*256 + oct*16) = o;
          }
        }
      }
    } else {
      if (mi == 0) conv_phase<0>(P, b, h0, combB, wgl, t - 256);
      else         conv_phase<1>(P, b, h0, combB, wgl, t - 256);
    }
    __syncthreads();
    if (mi == 0) {
      // stage X for mi=1
      for (int i = t*4; i < 12288; i += 2048) {
        int c = i >> 7, pix = i & 127;
        float4 v = *(const float4*)&P.x[(size_t)(b*C_ + 192 + c)*HW + h0*32 + pix];
        unsigned lo = (unsigned)f2bf(v.x) | ((unsigned)f2bf(v.y) << 16);
        unsigned hi = (unsigned)f2bf(v.z) | ((unsigned)f2bf(v.w) << 16);
        *(uint2*)(XB + c*256 + pix*2) = make_uint2(lo, hi);
      }
      __syncthreads();
    }
  }

  // stage w2 (overwrites w1 region)
  for (int i = t; i < 6912; i += 512) {
    int s = i / 2304, r = i - s*2304, mi2 = r / 1152, rr = r - mi2*1152;
    wlB[i] = f2bf(P.mw2[s][mi2*1152 + rr]);    // layout [(s*2+mi)*1152 + j*96 + c]
  }
  __syncthreads();

  // ---- layer2 + gate -> comb (MLP channels), all 512 threads ----
  {
    const int ct = t & 15, pt = (t >> 4) & 15, mi = t >> 8;
    const int c0 = ct*6, pix0 = pt*8;
    float wgc[3][6];
#pragma unroll
    for (int s = 0; s < 3; ++s)
#pragma unroll
      for (int i = 0; i < 6; ++i) wgc[s][i] = wgl[s*C_ + mi*192 + c0 + i];
    float acc[6][8];
#pragma unroll
    for (int i = 0; i < 6; ++i) {
      float ai = 0.f;
#pragma unroll
      for (int s = 0; s < 3; ++s) ai += wgc[s][i] * P.mb2[s][mi*96 + c0 + i];
#pragma unroll
      for (int p = 0; p < 8; ++p) acc[i][p] = ai;
    }
#pragma unroll
    for (int s = 0; s < 3; ++s)
#pragma unroll
      for (int jj = 0; jj < 12; ++jj) {
        const us8v hv = *(const us8v*)(hlB + (mi*36 + s*12 + jj)*256 + pix0*2);
        float hf[8];
#pragma unroll
        for (int p = 0; p < 8; ++p) hf[p] = bf2f(hv[p]);
        const unsigned short* wp = wlB + (s*2 + mi)*1152 + jj*96 + c0;
        float gw[6];
#pragma unroll
        for (int i = 0; i < 6; ++i) gw[i] = bf2f(wp[i]) * wgc[s][i];
#pragma unroll
        for (int i = 0; i < 6; ++i)
#pragma unroll
          for (int p = 0; p < 8; ++p) acc[i][p] += gw[i]*hf[p];
      }
#pragma unroll
    for (int i = 0; i < 6; ++i)
#pragma unroll
      for (int p = 0; p < 8; ++p) {
        const int pix = pix0 + p;
        const int kp2 = mi*96 + c0 + i;
        const int off = pix*768 + ((kp2*2) ^ ((pix & 15) << 4));
        *(unsigned short*)(combB + off) = f2bf(acc[i][p]);
      }
  }
  __syncthreads();

  // ---- MFMA GEMM: out[pix][d] = comb[pix][k'] * pwT[d][k'] ----
  {
    const int lane = t & 63, wv = t >> 6;
    const int wm = wv & 1, wn = wv >> 1;
    const int l15 = lane & 15, l4 = lane >> 4;
    f32x4 acc[4][6];
#pragma unroll
    for (int mt = 0; mt < 4; ++mt)
#pragma unroll
      for (int nt = 0; nt < 6; ++nt) acc[mt][nt] = (f32x4){0.f,0.f,0.f,0.f};
    const char* pwTb = (const char*)P.pwT;
#pragma unroll 2
    for (int ks = 0; ks < 12; ++ks) {
      const int k0 = ks*32 + l4*8;
      s16x8 af[4], bfr[6];
#pragma unroll
      for (int mt = 0; mt < 4; ++mt) {
        const int m = wm*64 + mt*16 + l15;
        af[mt] = *(const s16x8*)(combB + m*768 + ((2*k0) ^ ((m & 15) << 4)));
      }
#pragma unroll
      for (int nt = 0; nt < 6; ++nt) {
        const int d = wn*96 + nt*16 + l15;
        bfr[nt] = *(const s16x8*)(pwTb + (size_t)d*768 + 2*k0);
      }
#pragma unroll
      for (int mt = 0; mt < 4; ++mt)
#pragma unroll
        for (int nt = 0; nt < 6; ++nt)
          acc[mt][nt] = __builtin_amdgcn_mfma_f32_16x16x32_bf16(af[mt], bfr[nt], acc[mt][nt], 0, 0, 0);
    }
#pragma unroll
    for (int nt = 0; nt < 6; ++nt) {
      const int d = wn*96 + nt*16 + l15;
      const float pbv = P.pb[d];
#pragma unroll
      for (int mt = 0; mt < 4; ++mt) {
        const int pix = wm*64 + mt*16 + l4*4;
        float4 o;
        o.x = acc[mt][nt][0] + pbv;
        o.y = acc[mt][nt][1] + pbv;
        o.z = acc[mt][nt][2] + pbv;
        o.w = acc[mt][nt][3] + pbv;
        *(float4*)&P.out[(size_t)(b*C_ + d)*HW + (h0 + (pix >> 5))*32 + (pix & 31)] = o;
      }
    }
  }
}

// ---------------------------------------------------------------------------
extern "C" void kernel_launch(void* const* d_in, const int* in_sizes, int n_in,
                              void* d_out, int out_size, void* d_ws, size_t ws_size,
                              hipStream_t stream) {
  KParams P;
  P.x = (const float*)d_in[0];
  for (int s = 0; s < 3; ++s) {
    const int base = 1 + s * 6;
    P.mw1[s] = (const float*)d_in[base + 0];
    P.mb1[s] = (const float*)d_in[base + 1];
    P.mw2[s] = (const float*)d_in[base + 2];
    P.mb2[s] = (const float*)d_in[base + 3];
    P.cw[s]  = (const float*)d_in[base + 4];
    P.cb[s]  = (const float*)d_in[base + 5];
  }
  P.fw1 = (const float*)d_in[19]; P.fb1 = (const float*)d_in[20];
  P.fw2 = (const float*)d_in[21]; P.fb2 = (const float*)d_in[22];
  P.pw  = (const float*)d_in[23]; P.pb  = (const float*)d_in[24];
  float* w = (float*)d_ws;
  P.wg       = w;                            // 36864 floats
  P.H_part   = w + 36864;                    // 18432
  P.acv_part = w + 55296;                    // 49152
  P.pwT      = (unsigned short*)(w + 104448);// 147456 ushorts
  P.out = (float*)d_out;

  k_prep<<<144, 256, 0, stream>>>(P);
  k_sum <<<1024, 256, 0, stream>>>(P);
  k_gate<<<32, 128, 0, stream>>>(P);
  k_proj<<<256, 512, 0, stream>>>(P);
}